// Round 3
// baseline (666.330 us; speedup 1.0000x reference)
//
#include <hip/hip_runtime.h>

typedef __attribute__((ext_vector_type(8))) short bf16x8;
typedef __attribute__((ext_vector_type(4))) float f32x4;

__device__ __forceinline__ unsigned short f2bf(float f) {
  unsigned int u = __float_as_uint(f);
  u += 0x7FFF + ((u >> 16) & 1);   // round-to-nearest-even (finite values only)
  return (unsigned short)(u >> 16);
}

__device__ __forceinline__ void gload_lds16(const void* g, void* l) {
  __builtin_amdgcn_global_load_lds(
      (const __attribute__((address_space(1))) unsigned int*)g,
      (__attribute__((address_space(3))) unsigned int*)l,
      16, 0, 0);
}

// ---------------------------------------------------------------------------
// cast fp32 -> bf16 (vectorized)
// ---------------------------------------------------------------------------
__global__ void cast_f32_to_bf16(const float* __restrict__ in,
                                 unsigned short* __restrict__ out, int n4) {
  int stride = gridDim.x * blockDim.x;
  for (int i = blockIdx.x * blockDim.x + threadIdx.x; i < n4; i += stride) {
    float4 v = ((const float4*)in)[i];
    ushort4 o;
    o.x = f2bf(v.x); o.y = f2bf(v.y); o.z = f2bf(v.z); o.w = f2bf(v.w);
    ((ushort4*)out)[i] = o;
  }
}

// ---------------------------------------------------------------------------
// B^T GEMM: C[m][n] = sum_k A[m][k] * Bw[n][k]     (A: MxK, Bw: NxK row-major)
// 128x128 tile, BK=32, 4 waves (2x2), 16x16x32 bf16 MFMA, global_load_lds.
// EPI==0: write fp32 C.   EPI==1: qkv epilogue -> Q (scaled), K, V^T, bf16.
// ---------------------------------------------------------------------------
template<int EPI>
__global__ __launch_bounds__(256, 2)
void gemm_bt(const unsigned short* __restrict__ A,
             const unsigned short* __restrict__ Bw,
             float* __restrict__ Cf,
             unsigned short* __restrict__ Qo,
             unsigned short* __restrict__ Ko,
             unsigned short* __restrict__ Vo,
             int M, int N, int K, int Lseq) {
  __shared__ unsigned short As[128 * 32];
  __shared__ unsigned short Bs[128 * 32];
  const int tid = threadIdx.x;
  const int lane = tid & 63, w = tid >> 6;
  const int wm = w >> 1, wn = w & 1;
  const int g4 = lane >> 4, r16 = lane & 15;
  const long arow0 = (long)blockIdx.y * 128;
  const long brow0 = (long)blockIdx.x * 128;

  f32x4 acc[4][4];
#pragma unroll
  for (int i = 0; i < 4; ++i)
#pragma unroll
    for (int j = 0; j < 4; ++j) acc[i][j] = (f32x4){0.f, 0.f, 0.f, 0.f};

  for (int k0 = 0; k0 < K; k0 += 32) {
    // stage 8KB A-tile + 8KB B-tile; LDS linear [row][32] bf16 (64B rows)
#pragma unroll
    for (int c = 0; c < 2; ++c) {
      int off = (w << 11) + (c << 10) + (lane << 4);  // byte offset in tile
      int row = off >> 6;
      int cole = (off & 63) >> 1;                     // element col in [0,32)
      gload_lds16(A + (arow0 + row) * (long)K + k0 + cole,
                  (char*)As + (w << 11) + (c << 10));
      gload_lds16(Bw + (brow0 + row) * (long)K + k0 + cole,
                  (char*)Bs + (w << 11) + (c << 10));
    }
    __syncthreads();
    bf16x8 af[4], bf[4];
#pragma unroll
    for (int mf = 0; mf < 4; ++mf)
      af[mf] = *(const bf16x8*)((const char*)As +
                                ((64 * wm + 16 * mf + r16) << 6) + (g4 << 4));
#pragma unroll
    for (int nf = 0; nf < 4; ++nf)
      bf[nf] = *(const bf16x8*)((const char*)Bs +
                                ((64 * wn + 16 * nf + r16) << 6) + (g4 << 4));
#pragma unroll
    for (int mf = 0; mf < 4; ++mf)
#pragma unroll
      for (int nf = 0; nf < 4; ++nf)
        acc[mf][nf] = __builtin_amdgcn_mfma_f32_16x16x32_bf16(
            af[mf], bf[nf], acc[mf][nf], 0, 0, 0);
    __syncthreads();
  }

  const float qscale = 0.08838834764831845f;  // 1/sqrt(128), folded into Q
#pragma unroll
  for (int mf = 0; mf < 4; ++mf) {
#pragma unroll
    for (int nf = 0; nf < 4; ++nf) {
#pragma unroll
      for (int i = 0; i < 4; ++i) {
        long row = arow0 + 64 * wm + 16 * mf + 4 * g4 + i;  // C/D: row=(l>>4)*4+i
        long col = brow0 + 64 * wn + 16 * nf + r16;         //      col=l&15
        float v = acc[mf][nf][i];
        if (EPI == 0) {
          Cf[row * N + col] = v;
        } else {
          int which = (int)(col >> 11);      // 0:q 1:k 2:v
          int h = ((int)col >> 7) & 15;
          int d = (int)col & 127;
          int b = (int)(row >> 11);
          int l = (int)row & 2047;
          long bhead = (long)(b * 16 + h);
          if (which == 0)
            Qo[(bhead * Lseq + l) * 128 + d] = f2bf(v * qscale);
          else if (which == 1)
            Ko[(bhead * Lseq + l) * 128 + d] = f2bf(v);
          else
            Vo[(bhead * 128 + d) * Lseq + l] = f2bf(v);  // V transposed (D,L)
        }
      }
    }
  }
}

// ---------------------------------------------------------------------------
// Flash attention (causal). Q pre-scaled by 1/sqrt(D). RoPE skipped (exact
// no-op: identical rotation applied to q and k preserves dot products).
// Grid: (L/64, B*H). 4 waves; wave w owns S/O rows [16w,16w+16).
// K, Vt fragments read directly from global (per-head K/V = 1MB, L2-fit).
// ---------------------------------------------------------------------------
__global__ __launch_bounds__(256, 2)
void attn_fwd(const unsigned short* __restrict__ Q,
              const unsigned short* __restrict__ K,
              const unsigned short* __restrict__ Vt,
              unsigned short* __restrict__ Y, int L) {
  const int D = 128;
  const int qt = blockIdx.x, bh = blockIdx.y;
  const int tid = threadIdx.x, lane = tid & 63, w = tid >> 6;
  const int g4 = lane >> 4, r16 = lane & 15;
  const int q0 = qt * 64;
  __shared__ unsigned short P[4][16][72];  // +8 pad: row stride 144B -> 2-way max

  const unsigned short* Qh = Q + (long)bh * L * D;
  const unsigned short* Kh = K + (long)bh * L * D;
  const unsigned short* Vh = Vt + (long)bh * D * L;

  bf16x8 qf[4];
  {
    long qrow = q0 + 16 * w + r16;
#pragma unroll
    for (int ks = 0; ks < 4; ++ks)
      qf[ks] = *(const bf16x8*)(Qh + qrow * D + ks * 32 + g4 * 8);
  }
  f32x4 o[8];
#pragma unroll
  for (int j = 0; j < 8; ++j) o[j] = (f32x4){0.f, 0.f, 0.f, 0.f};
  float mrun[4] = {-1e30f, -1e30f, -1e30f, -1e30f};
  float lrun[4] = {0.f, 0.f, 0.f, 0.f};

  for (int kt = 0; kt <= qt; ++kt) {
    f32x4 s[4];
#pragma unroll
    for (int nf = 0; nf < 4; ++nf) s[nf] = (f32x4){0.f, 0.f, 0.f, 0.f};
#pragma unroll
    for (int ks = 0; ks < 4; ++ks) {
#pragma unroll
      for (int nf = 0; nf < 4; ++nf) {
        bf16x8 kf = *(const bf16x8*)(Kh + (long)(kt * 64 + 16 * nf + r16) * D +
                                     ks * 32 + g4 * 8);
        s[nf] = __builtin_amdgcn_mfma_f32_16x16x32_bf16(qf[ks], kf, s[nf], 0, 0, 0);
      }
    }
    const bool diag = (kt == qt);
#pragma unroll
    for (int i = 0; i < 4; ++i) {
      int qg = q0 + 16 * w + 4 * g4 + i;
      float sv[4];
      float rmax = -1e30f;
#pragma unroll
      for (int nf = 0; nf < 4; ++nf) {
        float t = s[nf][i];
        if (diag && (kt * 64 + 16 * nf + r16) > qg) t = -1e30f;
        sv[nf] = t;
        rmax = fmaxf(rmax, t);
      }
      rmax = fmaxf(rmax, __shfl_xor(rmax, 1));
      rmax = fmaxf(rmax, __shfl_xor(rmax, 2));
      rmax = fmaxf(rmax, __shfl_xor(rmax, 4));
      rmax = fmaxf(rmax, __shfl_xor(rmax, 8));
      float mnew = fmaxf(mrun[i], rmax);
      float corr = __expf(mrun[i] - mnew);
      mrun[i] = mnew;
      float rs = 0.f;
#pragma unroll
      for (int nf = 0; nf < 4; ++nf) {
        float pv = __expf(sv[nf] - mnew);
        P[w][4 * g4 + i][16 * nf + r16] = f2bf(pv);
        rs += pv;
      }
      rs += __shfl_xor(rs, 1);
      rs += __shfl_xor(rs, 2);
      rs += __shfl_xor(rs, 4);
      rs += __shfl_xor(rs, 8);
      lrun[i] = lrun[i] * corr + rs;
#pragma unroll
      for (int nf2 = 0; nf2 < 8; ++nf2) o[nf2][i] *= corr;
    }
    __syncthreads();
#pragma unroll
    for (int ks2 = 0; ks2 < 2; ++ks2) {
      bf16x8 pf = *(const bf16x8*)(&P[w][r16][ks2 * 32 + g4 * 8]);
#pragma unroll
      for (int nf2 = 0; nf2 < 8; ++nf2) {
        bf16x8 vf = *(const bf16x8*)(Vh + (long)(16 * nf2 + r16) * L + kt * 64 +
                                     ks2 * 32 + g4 * 8);
        o[nf2] = __builtin_amdgcn_mfma_f32_16x16x32_bf16(pf, vf, o[nf2], 0, 0, 0);
      }
    }
    __syncthreads();
  }
  const int b = bh >> 4, h = bh & 15;
#pragma unroll
  for (int nf2 = 0; nf2 < 8; ++nf2) {
#pragma unroll
    for (int i = 0; i < 4; ++i) {
      long row = (long)b * L + q0 + 16 * w + 4 * g4 + i;
      float v = o[nf2][i] / lrun[i];
      Y[row * 2048 + h * 128 + 16 * nf2 + r16] = f2bf(v);
    }
  }
}

// ---------------------------------------------------------------------------
extern "C" void kernel_launch(void* const* d_in, const int* in_sizes, int n_in,
                              void* d_out, int out_size, void* d_ws,
                              size_t ws_size, hipStream_t stream) {
  const float* x = (const float*)d_in[0];
  const float* wa = (const float*)d_in[1];
  const float* wp = (const float*)d_in[2];
  float* out = (float*)d_out;
  const int B = 2, L = 2048, C = 2048;
  const int M = B * L;  // 4096

  unsigned short* xb = (unsigned short*)d_ws;
  unsigned short* wab = xb + (size_t)M * C;          // 8.4M
  unsigned short* wpb = wab + (size_t)3 * C * C;     // +12.6M
  unsigned short* Qb = wpb + (size_t)C * C;          // +4.2M
  unsigned short* Kb = Qb + (size_t)M * C;
  unsigned short* Vb = Kb + (size_t)M * C;
  unsigned short* Yb = Vb + (size_t)M * C;           // total ~112MB

  cast_f32_to_bf16<<<2048, 256, 0, stream>>>(x, xb, M * C / 4);
  cast_f32_to_bf16<<<2048, 256, 0, stream>>>(wa, wab, 3 * C * C / 4);
  cast_f32_to_bf16<<<1024, 256, 0, stream>>>(wp, wpb, C * C / 4);

  gemm_bt<1><<<dim3(3 * C / 128, M / 128), 256, 0, stream>>>(
      xb, wab, nullptr, Qb, Kb, Vb, M, 3 * C, C, L);

  attn_fwd<<<dim3(L / 64, B * 16), 256, 0, stream>>>(Qb, Kb, Vb, Yb, L);

  gemm_bt<0><<<dim3(C / 128, M / 128), 256, 0, stream>>>(
      Yb, wpb, out, nullptr, nullptr, nullptr, M, C, C, L);
}

// Round 4
// 551.560 us; speedup vs baseline: 1.2081x; 1.2081x over previous
//
#include <hip/hip_runtime.h>

typedef __attribute__((ext_vector_type(8))) short bf16x8;
typedef __attribute__((ext_vector_type(4))) float f32x4;

__device__ __forceinline__ unsigned short f2bf(float f) {
  unsigned int u = __float_as_uint(f);
  u += 0x7FFF + ((u >> 16) & 1);   // round-to-nearest-even (finite values only)
  return (unsigned short)(u >> 16);
}

__device__ __forceinline__ void gload_lds16(const void* g, void* l) {
  __builtin_amdgcn_global_load_lds(
      (const __attribute__((address_space(1))) unsigned int*)g,
      (__attribute__((address_space(3))) unsigned int*)l,
      16, 0, 0);
}

// ---------------------------------------------------------------------------
// cast fp32 -> bf16 (vectorized)
// ---------------------------------------------------------------------------
__global__ void cast_f32_to_bf16(const float* __restrict__ in,
                                 unsigned short* __restrict__ out, int n4) {
  int stride = gridDim.x * blockDim.x;
  for (int i = blockIdx.x * blockDim.x + threadIdx.x; i < n4; i += stride) {
    float4 v = ((const float4*)in)[i];
    ushort4 o;
    o.x = f2bf(v.x); o.y = f2bf(v.y); o.z = f2bf(v.z); o.w = f2bf(v.w);
    ((ushort4*)out)[i] = o;
  }
}

// ---------------------------------------------------------------------------
// B^T GEMM: C[m][n] = sum_k A[m][k] * Bw[n][k]     (A: MxK, Bw: NxK row-major)
// 128x128 tile, BK=32, 4 waves (2x2), 16x16x32 bf16 MFMA, global_load_lds.
// EPI==0: write fp32 C.   EPI==1: qkv epilogue -> Q (scaled), K, V^T, bf16.
// ---------------------------------------------------------------------------
template<int EPI>
__global__ __launch_bounds__(256, 2)
void gemm_bt(const unsigned short* __restrict__ A,
             const unsigned short* __restrict__ Bw,
             float* __restrict__ Cf,
             unsigned short* __restrict__ Qo,
             unsigned short* __restrict__ Ko,
             unsigned short* __restrict__ Vo,
             int M, int N, int K, int Lseq) {
  __shared__ unsigned short As[128 * 32];
  __shared__ unsigned short Bs[128 * 32];
  const int tid = threadIdx.x;
  const int lane = tid & 63, w = tid >> 6;
  const int wm = w >> 1, wn = w & 1;
  const int g4 = lane >> 4, r16 = lane & 15;
  const long arow0 = (long)blockIdx.y * 128;
  const long brow0 = (long)blockIdx.x * 128;

  f32x4 acc[4][4];
#pragma unroll
  for (int i = 0; i < 4; ++i)
#pragma unroll
    for (int j = 0; j < 4; ++j) acc[i][j] = (f32x4){0.f, 0.f, 0.f, 0.f};

  for (int k0 = 0; k0 < K; k0 += 32) {
    // stage 8KB A-tile + 8KB B-tile; LDS linear [row][32] bf16 (64B rows)
#pragma unroll
    for (int c = 0; c < 2; ++c) {
      int off = (w << 11) + (c << 10) + (lane << 4);  // byte offset in tile
      int row = off >> 6;
      int cole = (off & 63) >> 1;                     // element col in [0,32)
      gload_lds16(A + (arow0 + row) * (long)K + k0 + cole,
                  (char*)As + (w << 11) + (c << 10));
      gload_lds16(Bw + (brow0 + row) * (long)K + k0 + cole,
                  (char*)Bs + (w << 11) + (c << 10));
    }
    __syncthreads();
    bf16x8 af[4], bf[4];
#pragma unroll
    for (int mf = 0; mf < 4; ++mf)
      af[mf] = *(const bf16x8*)((const char*)As +
                                ((64 * wm + 16 * mf + r16) << 6) + (g4 << 4));
#pragma unroll
    for (int nf = 0; nf < 4; ++nf)
      bf[nf] = *(const bf16x8*)((const char*)Bs +
                                ((64 * wn + 16 * nf + r16) << 6) + (g4 << 4));
#pragma unroll
    for (int mf = 0; mf < 4; ++mf)
#pragma unroll
      for (int nf = 0; nf < 4; ++nf)
        acc[mf][nf] = __builtin_amdgcn_mfma_f32_16x16x32_bf16(
            af[mf], bf[nf], acc[mf][nf], 0, 0, 0);
    __syncthreads();
  }

  const float qscale = 0.08838834764831845f;  // 1/sqrt(128), folded into Q
#pragma unroll
  for (int mf = 0; mf < 4; ++mf) {
#pragma unroll
    for (int nf = 0; nf < 4; ++nf) {
#pragma unroll
      for (int i = 0; i < 4; ++i) {
        long row = arow0 + 64 * wm + 16 * mf + 4 * g4 + i;  // C/D: row=(l>>4)*4+i
        long col = brow0 + 64 * wn + 16 * nf + r16;         //      col=l&15
        float v = acc[mf][nf][i];
        if (EPI == 0) {
          Cf[row * N + col] = v;
        } else {
          int which = (int)(col >> 11);      // 0:q 1:k 2:v
          int h = ((int)col >> 7) & 15;
          int d = (int)col & 127;
          int b = (int)(row >> 11);
          int l = (int)row & 2047;
          long bhead = (long)(b * 16 + h);
          if (which == 0)
            Qo[(bhead * Lseq + l) * 128 + d] = f2bf(v * qscale);
          else if (which == 1)
            Ko[(bhead * Lseq + l) * 128 + d] = f2bf(v);
          else
            Vo[(bhead * 128 + d) * Lseq + l] = f2bf(v);  // V transposed (D,L)
        }
      }
    }
  }
}

// ---------------------------------------------------------------------------
// Flash attention (causal). Q pre-scaled by 1/sqrt(D). RoPE skipped (exact
// no-op: identical rotation applied to q and k preserves dot products).
// 1-D grid of 1024 blocks, swizzled so each XCD owns a contiguous group of
// 4 (b,h) heads (8MB K/V per XCD vs 64MB unswizzled). 4 waves; wave w owns
// rows [16w,16w+16). P is wave-private -> NO barriers anywhere.
// K/V fragment loads are BATCHED into registers (16 in flight) so latency is
// paid once per tile, and V's latency hides under the softmax VALU work.
// ---------------------------------------------------------------------------
__global__ __launch_bounds__(256, 2)
void attn_fwd(const unsigned short* __restrict__ Q,
              const unsigned short* __restrict__ K,
              const unsigned short* __restrict__ Vt,
              unsigned short* __restrict__ Y, int L) {
  const int D = 128;
  // swizzled decode: id = g + 8*((bh&3)*32 + qt), g = bh>>2
  const int id = blockIdx.x;
  const int g = id & 7, kk = id >> 3;
  const int bh = (g << 2) + (kk >> 5);
  const int qt = kk & 31;
  const int tid = threadIdx.x, lane = tid & 63, w = tid >> 6;
  const int g4 = lane >> 4, r16 = lane & 15;
  const int q0 = qt * 64;
  __shared__ unsigned short P[4][16][72];  // wave-private; +8 pad

  const unsigned short* Qh = Q + (long)bh * L * D;
  const unsigned short* Kh = K + (long)bh * L * D;
  const unsigned short* Vh = Vt + (long)bh * D * L;

  bf16x8 qf[4];
  {
    long qrow = q0 + 16 * w + r16;
#pragma unroll
    for (int ks = 0; ks < 4; ++ks)
      qf[ks] = *(const bf16x8*)(Qh + qrow * D + ks * 32 + g4 * 8);
  }
  f32x4 o[8];
#pragma unroll
  for (int j = 0; j < 8; ++j) o[j] = (f32x4){0.f, 0.f, 0.f, 0.f};
  float mrun[4] = {-1e30f, -1e30f, -1e30f, -1e30f};
  float lrun[4] = {0.f, 0.f, 0.f, 0.f};

  for (int kt = 0; kt <= qt; ++kt) {
    // ---- batch-load ALL K fragments (16 loads in flight, one drain) ----
    bf16x8 kf[4][4];
#pragma unroll
    for (int ks = 0; ks < 4; ++ks)
#pragma unroll
      for (int nf = 0; nf < 4; ++nf)
        kf[ks][nf] = *(const bf16x8*)(Kh +
            (long)(kt * 64 + 16 * nf + r16) * D + ks * 32 + g4 * 8);

    f32x4 s[4];
#pragma unroll
    for (int nf = 0; nf < 4; ++nf) s[nf] = (f32x4){0.f, 0.f, 0.f, 0.f};
#pragma unroll
    for (int ks = 0; ks < 4; ++ks)
#pragma unroll
      for (int nf = 0; nf < 4; ++nf)
        s[nf] = __builtin_amdgcn_mfma_f32_16x16x32_bf16(qf[ks], kf[ks][nf],
                                                        s[nf], 0, 0, 0);

    // ---- issue ALL V fragments now; softmax below hides their latency ----
    bf16x8 vf[2][8];
#pragma unroll
    for (int ks2 = 0; ks2 < 2; ++ks2)
#pragma unroll
      for (int nf2 = 0; nf2 < 8; ++nf2)
        vf[ks2][nf2] = *(const bf16x8*)(Vh +
            (long)(16 * nf2 + r16) * L + kt * 64 + ks2 * 32 + g4 * 8);

    const bool diag = (kt == qt);
#pragma unroll
    for (int i = 0; i < 4; ++i) {
      int qg = q0 + 16 * w + 4 * g4 + i;
      float sv[4];
      float rmax = -1e30f;
#pragma unroll
      for (int nf = 0; nf < 4; ++nf) {
        float t = s[nf][i];
        if (diag && (kt * 64 + 16 * nf + r16) > qg) t = -1e30f;
        sv[nf] = t;
        rmax = fmaxf(rmax, t);
      }
      rmax = fmaxf(rmax, __shfl_xor(rmax, 1));
      rmax = fmaxf(rmax, __shfl_xor(rmax, 2));
      rmax = fmaxf(rmax, __shfl_xor(rmax, 4));
      rmax = fmaxf(rmax, __shfl_xor(rmax, 8));
      float mnew = fmaxf(mrun[i], rmax);
      float corr = __expf(mrun[i] - mnew);
      mrun[i] = mnew;
      float rs = 0.f;
#pragma unroll
      for (int nf = 0; nf < 4; ++nf) {
        float pv = __expf(sv[nf] - mnew);
        P[w][4 * g4 + i][16 * nf + r16] = f2bf(pv);
        rs += pv;
      }
      rs += __shfl_xor(rs, 1);
      rs += __shfl_xor(rs, 2);
      rs += __shfl_xor(rs, 4);
      rs += __shfl_xor(rs, 8);
      lrun[i] = lrun[i] * corr + rs;
#pragma unroll
      for (int nf2 = 0; nf2 < 8; ++nf2) o[nf2][i] *= corr;
    }
    // P is wave-private: no barrier. Compiler orders LDS write->read via lgkmcnt.
#pragma unroll
    for (int ks2 = 0; ks2 < 2; ++ks2) {
      bf16x8 pf = *(const bf16x8*)(&P[w][r16][ks2 * 32 + g4 * 8]);
#pragma unroll
      for (int nf2 = 0; nf2 < 8; ++nf2)
        o[nf2] = __builtin_amdgcn_mfma_f32_16x16x32_bf16(pf, vf[ks2][nf2],
                                                         o[nf2], 0, 0, 0);
    }
  }
  const int b = bh >> 4, h = bh & 15;
#pragma unroll
  for (int nf2 = 0; nf2 < 8; ++nf2) {
#pragma unroll
    for (int i = 0; i < 4; ++i) {
      long row = (long)b * L + q0 + 16 * w + 4 * g4 + i;
      float v = o[nf2][i] / lrun[i];
      Y[row * 2048 + h * 128 + 16 * nf2 + r16] = f2bf(v);
    }
  }
}

// ---------------------------------------------------------------------------
extern "C" void kernel_launch(void* const* d_in, const int* in_sizes, int n_in,
                              void* d_out, int out_size, void* d_ws,
                              size_t ws_size, hipStream_t stream) {
  const float* x = (const float*)d_in[0];
  const float* wa = (const float*)d_in[1];
  const float* wp = (const float*)d_in[2];
  float* out = (float*)d_out;
  const int B = 2, L = 2048, C = 2048;
  const int M = B * L;  // 4096

  unsigned short* xb = (unsigned short*)d_ws;
  unsigned short* wab = xb + (size_t)M * C;          // 8.4M
  unsigned short* wpb = wab + (size_t)3 * C * C;     // +12.6M
  unsigned short* Qb = wpb + (size_t)C * C;          // +4.2M
  unsigned short* Kb = Qb + (size_t)M * C;
  unsigned short* Vb = Kb + (size_t)M * C;
  unsigned short* Yb = Vb + (size_t)M * C;           // total ~112MB

  cast_f32_to_bf16<<<2048, 256, 0, stream>>>(x, xb, M * C / 4);
  cast_f32_to_bf16<<<2048, 256, 0, stream>>>(wa, wab, 3 * C * C / 4);
  cast_f32_to_bf16<<<1024, 256, 0, stream>>>(wp, wpb, C * C / 4);

  gemm_bt<1><<<dim3(3 * C / 128, M / 128), 256, 0, stream>>>(
      xb, wab, nullptr, Qb, Kb, Vb, M, 3 * C, C, L);

  attn_fwd<<<1024, 256, 0, stream>>>(Qb, Kb, Vb, Yb, L);

  gemm_bt<0><<<dim3(C / 128, M / 128), 256, 0, stream>>>(
      Yb, wpb, out, nullptr, nullptr, nullptr, M, C, C, L);
}

// Round 6
// 343.706 us; speedup vs baseline: 1.9387x; 1.6047x over previous
//
#include <hip/hip_runtime.h>

typedef __attribute__((ext_vector_type(8))) short bf16x8;
typedef __attribute__((ext_vector_type(4))) float f32x4;

__device__ __forceinline__ unsigned short f2bf(float f) {
  unsigned int u = __float_as_uint(f);
  u += 0x7FFF + ((u >> 16) & 1);   // round-to-nearest-even (finite values only)
  return (unsigned short)(u >> 16);
}

__device__ __forceinline__ void gload_lds16(const void* g, void* l) {
  __builtin_amdgcn_global_load_lds(
      (const __attribute__((address_space(1))) unsigned int*)g,
      (__attribute__((address_space(3))) unsigned int*)l,
      16, 0, 0);
}

// ---------------------------------------------------------------------------
// cast fp32 -> bf16 (vectorized)
// ---------------------------------------------------------------------------
__global__ void cast_f32_to_bf16(const float* __restrict__ in,
                                 unsigned short* __restrict__ out, int n4) {
  int stride = gridDim.x * blockDim.x;
  for (int i = blockIdx.x * blockDim.x + threadIdx.x; i < n4; i += stride) {
    float4 v = ((const float4*)in)[i];
    ushort4 o;
    o.x = f2bf(v.x); o.y = f2bf(v.y); o.z = f2bf(v.z); o.w = f2bf(v.w);
    ((ushort4*)out)[i] = o;
  }
}

// ---------------------------------------------------------------------------
// B^T GEMM: C[m][n] = sum_k A[m][k] * Bw[n][k]     (A: MxK, Bw: NxK row-major)
// 128x128 tile, BK=32, 4 waves (2x2), 16x16x32 bf16 MFMA, global_load_lds.
// EPI==0: write fp32 C.   EPI==1: qkv epilogue -> Q (scaled), K, V^T, bf16.
// ---------------------------------------------------------------------------
template<int EPI>
__global__ __launch_bounds__(256, 2)
void gemm_bt(const unsigned short* __restrict__ A,
             const unsigned short* __restrict__ Bw,
             float* __restrict__ Cf,
             unsigned short* __restrict__ Qo,
             unsigned short* __restrict__ Ko,
             unsigned short* __restrict__ Vo,
             int M, int N, int K, int Lseq) {
  __shared__ unsigned short As[128 * 32];
  __shared__ unsigned short Bs[128 * 32];
  const int tid = threadIdx.x;
  const int lane = tid & 63, w = tid >> 6;
  const int wm = w >> 1, wn = w & 1;
  const int g4 = lane >> 4, r16 = lane & 15;
  const long arow0 = (long)blockIdx.y * 128;
  const long brow0 = (long)blockIdx.x * 128;

  f32x4 acc[4][4];
#pragma unroll
  for (int i = 0; i < 4; ++i)
#pragma unroll
    for (int j = 0; j < 4; ++j) acc[i][j] = (f32x4){0.f, 0.f, 0.f, 0.f};

  for (int k0 = 0; k0 < K; k0 += 32) {
    // stage 8KB A-tile + 8KB B-tile; LDS linear [row][32] bf16 (64B rows)
#pragma unroll
    for (int c = 0; c < 2; ++c) {
      int off = (w << 11) + (c << 10) + (lane << 4);  // byte offset in tile
      int row = off >> 6;
      int cole = (off & 63) >> 1;                     // element col in [0,32)
      gload_lds16(A + (arow0 + row) * (long)K + k0 + cole,
                  (char*)As + (w << 11) + (c << 10));
      gload_lds16(Bw + (brow0 + row) * (long)K + k0 + cole,
                  (char*)Bs + (w << 11) + (c << 10));
    }
    __syncthreads();
    bf16x8 af[4], bf[4];
#pragma unroll
    for (int mf = 0; mf < 4; ++mf)
      af[mf] = *(const bf16x8*)((const char*)As +
                                ((64 * wm + 16 * mf + r16) << 6) + (g4 << 4));
#pragma unroll
    for (int nf = 0; nf < 4; ++nf)
      bf[nf] = *(const bf16x8*)((const char*)Bs +
                                ((64 * wn + 16 * nf + r16) << 6) + (g4 << 4));
#pragma unroll
    for (int mf = 0; mf < 4; ++mf)
#pragma unroll
      for (int nf = 0; nf < 4; ++nf)
        acc[mf][nf] = __builtin_amdgcn_mfma_f32_16x16x32_bf16(
            af[mf], bf[nf], acc[mf][nf], 0, 0, 0);
    __syncthreads();
  }

  const float qscale = 0.08838834764831845f;  // 1/sqrt(128), folded into Q
#pragma unroll
  for (int mf = 0; mf < 4; ++mf) {
#pragma unroll
    for (int nf = 0; nf < 4; ++nf) {
#pragma unroll
      for (int i = 0; i < 4; ++i) {
        long row = arow0 + 64 * wm + 16 * mf + 4 * g4 + i;  // C/D: row=(l>>4)*4+i
        long col = brow0 + 64 * wn + 16 * nf + r16;         //      col=l&15
        float v = acc[mf][nf][i];
        if (EPI == 0) {
          Cf[row * N + col] = v;
        } else {
          int which = (int)(col >> 11);      // 0:q 1:k 2:v
          int h = ((int)col >> 7) & 15;
          int d = (int)col & 127;
          int b = (int)(row >> 11);
          int l = (int)row & 2047;
          long bhead = (long)(b * 16 + h);
          if (which == 0)
            Qo[(bhead * Lseq + l) * 128 + d] = f2bf(v * qscale);
          else if (which == 1)
            Ko[(bhead * Lseq + l) * 128 + d] = f2bf(v);
          else
            Vo[(bhead * 128 + d) * Lseq + l] = f2bf(v);  // V transposed (D,L)
        }
      }
    }
  }
}

// ---------------------------------------------------------------------------
// Flash attention (causal). Q pre-scaled by 1/sqrt(D). RoPE skipped (exact
// no-op: identical rotation applied to q and k preserves dot products).
// v3: 2-phase LDS pipeline (T3-minimum). K/V tiles double-buffered in LDS via
// global_load_lds (zero VGPR cost, compiler can't sink it), counted
// s_waitcnt vmcnt(8) so next tile's 8 loads stay in flight across barriers.
// LDS tiles XOR-swizzled (cb ^= row&7 on 16B units) via pre-swizzled global
// source (linear gload_lds dest) -> 2-way bank conflicts (free).
// Grid swizzled: XCD-local heads, longest blocks (qt=31) first.
// ---------------------------------------------------------------------------
__global__ __launch_bounds__(256, 2)
void attn_fwd(const unsigned short* __restrict__ Q,
              const unsigned short* __restrict__ K,
              const unsigned short* __restrict__ Vt,
              unsigned short* __restrict__ Y, int L) {
  const int D = 128;
  const int id = blockIdx.x;
  const int g = id & 7, kk = id >> 3;
  const int bh = (g << 2) + (kk >> 5);
  const int qt = 31 - (kk & 31);          // longest first
  const int tid = threadIdx.x, lane = tid & 63, w = tid >> 6;
  const int g4 = lane >> 4, r16 = lane & 15;
  const int q0 = qt * 64;

  __shared__ unsigned short Klds[2 * 64 * 128];   // 2 x 16KB
  __shared__ unsigned short Vlds[2 * 128 * 64];   // 2 x 16KB
  __shared__ unsigned short P[4][16][72];         // wave-private; +8 pad

  const unsigned short* Qh = Q + (long)bh * L * D;
  const unsigned short* Kh = K + (long)bh * L * D;
  const unsigned short* Vh = Vt + (long)bh * D * L;

  // stage one 64-key tile (K: [64][128], V^T: [128][64]) into buffer buf_.
  // LDS dest is linear (wave-uniform base, HW adds lane*16); the global
  // SOURCE is pre-swizzled: 16B-block index cb_src = cb_lds ^ (row & 7).
#define STAGE_TILE(kt_, buf_)                                                 \
  do {                                                                        \
    const int kbase_ = (kt_) * 64;                                            \
    _Pragma("unroll")                                                         \
    for (int r_ = 0; r_ < 4; ++r_) {                                          \
      int off_ = (tid << 4) + (r_ << 12);                                     \
      int krow_ = off_ >> 8, kcb_ = (off_ >> 4) & 15;                         \
      int kcbs_ = kcb_ ^ (krow_ & 7);                                         \
      gload_lds16(Kh + (long)(kbase_ + krow_) * 128 + kcbs_ * 8,              \
                  (char*)Klds + (buf_)*16384 + (w << 10) + (r_ << 12));       \
      int vrow_ = off_ >> 7, vcb_ = (off_ >> 4) & 7;                          \
      int vcbs_ = vcb_ ^ (vrow_ & 7);                                         \
      gload_lds16(Vh + (long)vrow_ * L + kbase_ + vcbs_ * 8,                  \
                  (char*)Vlds + (buf_)*16384 + (w << 10) + (r_ << 12));       \
    }                                                                         \
  } while (0)

  bf16x8 qf[4];
  {
    long qrow = q0 + 16 * w + r16;
#pragma unroll
    for (int ks = 0; ks < 4; ++ks)
      qf[ks] = *(const bf16x8*)(Qh + qrow * D + ks * 32 + g4 * 8);
  }
  f32x4 o[8];
#pragma unroll
  for (int j = 0; j < 8; ++j) o[j] = (f32x4){0.f, 0.f, 0.f, 0.f};
  float mrun[4] = {-1e30f, -1e30f, -1e30f, -1e30f};
  float lrun[4] = {0.f, 0.f, 0.f, 0.f};

  int cur = 0;
  STAGE_TILE(0, 0);

  for (int kt = 0; kt <= qt; ++kt) {
    if (kt < qt) {
      STAGE_TILE(kt + 1, cur ^ 1);
      asm volatile("s_waitcnt vmcnt(8)" ::: "memory");  // tile kt landed; kt+1 in flight
    } else {
      asm volatile("s_waitcnt vmcnt(0)" ::: "memory");
    }
    __builtin_amdgcn_s_barrier();   // whole tile visible to all waves

    const char* Kl = (const char*)Klds + cur * 16384;
    const char* Vl = (const char*)Vlds + cur * 16384;

    f32x4 s[4];
#pragma unroll
    for (int nf = 0; nf < 4; ++nf) s[nf] = (f32x4){0.f, 0.f, 0.f, 0.f};
#pragma unroll
    for (int ks = 0; ks < 4; ++ks) {
#pragma unroll
      for (int nf = 0; nf < 4; ++nf) {
        int row = 16 * nf + r16;
        bf16x8 kf = *(const bf16x8*)(Kl + row * 256 +
                                     (((ks * 4 + g4) ^ (row & 7)) << 4));
        s[nf] = __builtin_amdgcn_mfma_f32_16x16x32_bf16(qf[ks], kf, s[nf], 0, 0, 0);
      }
    }

    const bool diag = (kt == qt);
#pragma unroll
    for (int i = 0; i < 4; ++i) {
      int qg = q0 + 16 * w + 4 * g4 + i;
      float sv[4];
      float rmax = -1e30f;
#pragma unroll
      for (int nf = 0; nf < 4; ++nf) {
        float t = s[nf][i];
        if (diag && (kt * 64 + 16 * nf + r16) > qg) t = -1e30f;
        sv[nf] = t;
        rmax = fmaxf(rmax, t);
      }
      rmax = fmaxf(rmax, __shfl_xor(rmax, 1));
      rmax = fmaxf(rmax, __shfl_xor(rmax, 2));
      rmax = fmaxf(rmax, __shfl_xor(rmax, 4));
      rmax = fmaxf(rmax, __shfl_xor(rmax, 8));
      float mnew = fmaxf(mrun[i], rmax);
      float corr = __expf(mrun[i] - mnew);
      mrun[i] = mnew;
      float rs = 0.f;
#pragma unroll
      for (int nf = 0; nf < 4; ++nf) {
        float pv = __expf(sv[nf] - mnew);
        P[w][4 * g4 + i][16 * nf + r16] = f2bf(pv);
        rs += pv;
      }
      rs += __shfl_xor(rs, 1);
      rs += __shfl_xor(rs, 2);
      rs += __shfl_xor(rs, 4);
      rs += __shfl_xor(rs, 8);
      lrun[i] = lrun[i] * corr + rs;
#pragma unroll
      for (int nf2 = 0; nf2 < 8; ++nf2) o[nf2][i] *= corr;
    }
    // P is wave-private: compiler lgkmcnt ordering suffices (no barrier).
#pragma unroll
    for (int ks2 = 0; ks2 < 2; ++ks2) {
      bf16x8 pf = *(const bf16x8*)(&P[w][r16][ks2 * 32 + g4 * 8]);
#pragma unroll
      for (int nf2 = 0; nf2 < 8; ++nf2) {
        int row = 16 * nf2 + r16;
        bf16x8 vf = *(const bf16x8*)(Vl + row * 128 +
                                     (((ks2 * 4 + g4) ^ (row & 7)) << 4));
        o[nf2] = __builtin_amdgcn_mfma_f32_16x16x32_bf16(pf, vf, o[nf2], 0, 0, 0);
      }
    }
    asm volatile("" ::: "memory");  // keep buf[cur] reads above barrier B
    __builtin_amdgcn_s_barrier();   // all waves done with buf[cur]
    cur ^= 1;
  }
#undef STAGE_TILE

  const int b = bh >> 4, h = bh & 15;
#pragma unroll
  for (int nf2 = 0; nf2 < 8; ++nf2) {
#pragma unroll
    for (int i = 0; i < 4; ++i) {
      long row = (long)b * L + q0 + 16 * w + 4 * g4 + i;
      float v = o[nf2][i] / lrun[i];
      Y[row * 2048 + h * 128 + 16 * nf2 + r16] = f2bf(v);
    }
  }
}

// ---------------------------------------------------------------------------
extern "C" void kernel_launch(void* const* d_in, const int* in_sizes, int n_in,
                              void* d_out, int out_size, void* d_ws,
                              size_t ws_size, hipStream_t stream) {
  const float* x = (const float*)d_in[0];
  const float* wa = (const float*)d_in[1];
  const float* wp = (const float*)d_in[2];
  float* out = (float*)d_out;
  const int B = 2, L = 2048, C = 2048;
  const int M = B * L;  // 4096

  unsigned short* xb = (unsigned short*)d_ws;
  unsigned short* wab = xb + (size_t)M * C;          // 8.4M
  unsigned short* wpb = wab + (size_t)3 * C * C;     // +12.6M
  unsigned short* Qb = wpb + (size_t)C * C;          // +4.2M
  unsigned short* Kb = Qb + (size_t)M * C;
  unsigned short* Vb = Kb + (size_t)M * C;
  unsigned short* Yb = Vb + (size_t)M * C;           // total ~112MB

  cast_f32_to_bf16<<<2048, 256, 0, stream>>>(x, xb, M * C / 4);
  cast_f32_to_bf16<<<2048, 256, 0, stream>>>(wa, wab, 3 * C * C / 4);
  cast_f32_to_bf16<<<1024, 256, 0, stream>>>(wp, wpb, C * C / 4);

  gemm_bt<1><<<dim3(3 * C / 128, M / 128), 256, 0, stream>>>(
      xb, wab, nullptr, Qb, Kb, Vb, M, 3 * C, C, L);

  attn_fwd<<<1024, 256, 0, stream>>>(Qb, Kb, Vb, Yb, L);

  gemm_bt<0><<<dim3(C / 128, M / 128), 256, 0, stream>>>(
      Yb, wpb, out, nullptr, nullptr, nullptr, M, C, C, L);
}